// Round 4
// baseline (6791.908 us; speedup 1.0000x reference)
//
#include <hip/hip_runtime.h>
#include <math.h>

#define DDIM 512
#define TLEN 128
#define RB   8
#define NWG  (256 / RB)        // 32 workgroups
#define VDIM 32000
#define NWAVE 8                // 512 threads / 64

typedef _Float16 f16x8 __attribute__((ext_vector_type(8)));
typedef float    f32x4 __attribute__((ext_vector_type(4)));
typedef _Float16 h2    __attribute__((ext_vector_type(2)));

#define SROW_ST 264   // dwords per f16-pair state row
#define F32_ST  520   // dwords per f32 LDS row

__device__ __forceinline__ unsigned int pkh2(float a, float b) {
  h2 v; v.x = (_Float16)a; v.y = (_Float16)b;
  return __builtin_bit_cast(unsigned int, v);
}

__device__ __forceinline__ float tanh_fast(float x) {
#if __has_builtin(__builtin_amdgcn_exp2f) && __has_builtin(__builtin_amdgcn_rcpf)
  const float e = __builtin_amdgcn_exp2f(x * 2.885390081777927f);  // 2*log2(e)
  return 1.f - 2.f * __builtin_amdgcn_rcpf(e + 1.f);
#else
  const float e = exp2f(x * 2.885390081777927f);
  return 1.f - 2.f / (e + 1.f);
#endif
}

// ---- pack diffusion into MFMA A-fragment order ------------------------------
// frag (it 0..31, kt 0..15), lane l, elem e: val = diff[it*16+(l&15)][kt*32+(l>>4)*8+e]
// stored as uint4 (8 f16) at element index (it*16+kt)*64 + l
__global__ __launch_bounds__(256) void pack_diffusion(
    const float* __restrict__ A, uint4* __restrict__ pk)
{
  const int slot = blockIdx.x * 256 + threadIdx.x;   // 0..32767
  const int l  = slot & 63;
  const int fr = slot >> 6;
  const int kt = fr & 15;
  const int it = fr >> 4;
  const float* src = A + (size_t)(it * 16 + (l & 15)) * DDIM + kt * 32 + (l >> 4) * 8;
  pk[slot] = make_uint4(pkh2(src[0], src[1]), pkh2(src[2], src[3]),
                        pkh2(src[4], src[5]), pkh2(src[6], src[7]));
}

// ---- recurrence: one WG = 8 batch rows, MFMA matvec -------------------------
__global__ __launch_bounds__(512, 2) void attractor_recurrence(
    const int*   __restrict__ tokens,
    const float* __restrict__ embed,
    const uint4* __restrict__ Apk,
    const float* __restrict__ gamma_p,
    const float* __restrict__ beta_p,
    float*       __restrict__ comb_out)   // [256][512]
{
  const int tid   = threadIdx.x;
  const int w     = tid >> 6;
  const int l     = tid & 63;
  const int g     = l >> 4;
  const int rl    = l & 7;            // lane's r ((l&15)&7)
  const int row0  = blockIdx.x * RB;
  const int wbase = w * 64;

  __shared__ unsigned int srow[RB * SROW_ST];   // f16-pair state rows
  __shared__ float  sigl[RB * F32_ST];
  __shared__ float  fastl[RB * F32_ST];
  __shared__ float4 redc[NWAVE][RB];
  __shared__ float4 redt[NWAVE][6];
  __shared__ float4 carryl[RB];                 // {Σfast, ||fast||, ||slow||², 0}

  for (int x = tid; x < RB * SROW_ST; x += 512) srow[x] = 0u;
  for (int x = tid; x < RB * F32_ST;  x += 512) fastl[x] = 0.f;
  if (tid < RB) carryl[tid] = make_float4(0.f, 0.f, 0.f, 0.f);

  const float gamma = gamma_p[0];
  const float bss   = beta_p[0] * 0.5f;   // beta * SIGNAL_SCALE

  float fs[4][4], sl[4][4];               // state in MFMA C-layout [mt][reg]
  #pragma unroll
  for (int mt = 0; mt < 4; ++mt)
    #pragma unroll
    for (int q = 0; q < 4; ++q) { fs[mt][q] = 0.f; sl[mt][q] = 0.f; }
  float smean_lane = 0.f;                 // Σ fast (lane's r)
  float sl2_lane   = 0.f;                 // ||slow||² (lane's r)

  // prologue: prefetch embed gather for t=0
  float evc[RB];
  #pragma unroll
  for (int r = 0; r < RB; ++r) {
    const int tok = tokens[(row0 + r) * TLEN + 0];
    evc[r] = embed[(size_t)tok * DDIM + tid];
  }

  __syncthreads();

  for (int t = 0; t < TLEN; ++t) {
    //================ thread-per-column section (i = tid) ==================
    const int i = tid;
    // issue next token's embed gather ASAP (hides HBM latency under conv steps)
    const int tn = (t + 1 < TLEN) ? t + 1 : t;
    float evn[RB];
    #pragma unroll
    for (int r = 0; r < RB; ++r) {
      const int tok = tokens[(row0 + r) * TLEN + tn];
      evn[r] = embed[(size_t)tok * DDIM + i];
    }

    float ctxv[RB], invfn[RB], fn2v[RB], smn[RB];
    #pragma unroll
    for (int r = 0; r < RB; ++r) {
      const float4 cy = carryl[r];
      smn[r]   = cy.x;
      invfn[r] = 1.f / (cy.y + 1e-6f);
      fn2v[r]  = cy.y * cy.y;
      ctxv[r]  = fastl[r * F32_ST + i] * invfn[r];
    }
    // fused WG reduction: per r {Σev, Σev², Σ ev·ctx}
    float red[24];
    #pragma unroll
    for (int r = 0; r < RB; ++r) {
      red[r]          = evc[r];
      red[RB + r]     = evc[r] * evc[r];
      red[2 * RB + r] = evc[r] * ctxv[r];
    }
    #pragma unroll
    for (int off = 32; off >= 1; off >>= 1)
      #pragma unroll
      for (int q = 0; q < 24; ++q)
        red[q] += __shfl_xor(red[q], off);
    if (l == 0) {
      #pragma unroll
      for (int q6 = 0; q6 < 6; ++q6)
        redt[w][q6] = make_float4(red[q6*4], red[q6*4+1], red[q6*4+2], red[q6*4+3]);
    }
    __syncthreads();
    #pragma unroll
    for (int q = 0; q < 24; ++q) red[q] = 0.f;
    #pragma unroll
    for (int wv = 0; wv < NWAVE; ++wv)
      #pragma unroll
      for (int q6 = 0; q6 < 6; ++q6) {
        const float4 v = redt[wv][q6];
        red[q6*4]   += v.x; red[q6*4+1] += v.y;
        red[q6*4+2] += v.z; red[q6*4+3] += v.w;
      }
    // LN + signal per r
    #pragma unroll
    for (int r = 0; r < RB; ++r) {
      const float sev = red[r], sev2 = red[RB + r], sevc = red[2*RB + r];
      const float mu   = sev * (1.f / DDIM);
      float var = sev2 * (1.f / DDIM) - mu * mu;
      var = fmaxf(var, 0.f);
      const float inv  = rsqrtf(var + 1e-5f);
      const float n2y  = (float)DDIM * var / (var + 1e-5f);     // ||y||²
      const float invn = 1.f / fmaxf(sqrtf(n2y), 1e-12f);
      const float bi   = inv * invn;                            // base=(ev-mu)*bi
      const float sctx = invfn[r] * smn[r];                     // Σctx
      const float bdot = bi * (sevc - mu * sctx);               // base·ctx
      const float b2   = n2y * invn * invn;                     // ||base||²
      const float cn2  = fn2v[r] * invfn[r] * invfn[r];         // ||ctx||²
      const float sg2  = b2 + 2.f * gamma * bdot + gamma * gamma * cn2;
      const float isig = 1.f / (sqrtf(fmaxf(sg2, 0.f)) + 1e-6f);
      sigl[r * F32_ST + i] = ((evc[r] - mu) * bi + gamma * ctxv[r]) * isig;
    }
    __syncthreads();

    //================ MFMA section (wave w, lane l) ========================
    f32x4 sgf[4];
    #pragma unroll
    for (int mt = 0; mt < 4; ++mt)
      sgf[mt] = *(const f32x4*)&sigl[rl * F32_ST + wbase + mt * 16 + g * 4];

    const uint4* apw = Apk + (size_t)(w * 64) * 64 + l;

    #pragma unroll 1
    for (int k = 0; k < 4; ++k) {
      f32x4 C[4];
      #pragma unroll
      for (int mt = 0; mt < 4; ++mt) C[mt] = (f32x4){0.f, 0.f, 0.f, 0.f};

      uint4 ab[4][4];                      // 4-deep A prefetch pipeline
      #pragma unroll
      for (int p = 0; p < 4; ++p)
        #pragma unroll
        for (int mt = 0; mt < 4; ++mt)
          ab[p][mt] = apw[(size_t)(mt * 16 + p) * 64];

      #pragma unroll
      for (int kt = 0; kt < 16; ++kt) {
        const int p = kt & 3;
        const f16x8 bf = *(const f16x8*)&srow[rl * SROW_ST + kt * 16 + g * 4];
        uint4 cur[4];
        #pragma unroll
        for (int mt = 0; mt < 4; ++mt) cur[mt] = ab[p][mt];
        if (kt < 12) {
          #pragma unroll
          for (int mt = 0; mt < 4; ++mt)
            ab[p][mt] = apw[(size_t)(mt * 16 + kt + 4) * 64];
        }
        #pragma unroll
        for (int mt = 0; mt < 4; ++mt)
          C[mt] = __builtin_amdgcn_mfma_f32_16x16x32_f16(
                      __builtin_bit_cast(f16x8, cur[mt]), bf, C[mt], 0, 0, 0);
      }

      // elementwise update + fused {Σsp, Σsp², Σslow·sp} reduction (sp in fs)
      const float meanr = smean_lane * (1.f / DDIM);
      const bool last = (k == 3);
      float vs = 0.f, v2 = 0.f, vx = 0.f;
      #pragma unroll
      for (int mt = 0; mt < 4; ++mt)
        #pragma unroll
        for (int q = 0; q < 4; ++q) {
          const float s  = fs[mt][q];
          const float th = tanh_fast(s - meanr);
          const float dr = C[mt][q] + 0.008f * th + bss * sgf[mt][q] - 0.1f * s;
          const float sv = fmaf(0.04f, dr, s);   // nan_to_num/clip are no-ops
          fs[mt][q] = sv;
          vs += sv; v2 += sv * sv;
          if (last) vx += sl[mt][q] * sv;
        }
      #pragma unroll
      for (int off = 8; off <= 32; off <<= 1) {
        vs += __shfl_xor(vs, off);
        v2 += __shfl_xor(v2, off);
        vx += __shfl_xor(vx, off);
      }
      if (l < RB) redc[w][l] = make_float4(vs, v2, vx, 0.f);
      __syncthreads();
      float S = 0.f, S2 = 0.f, SX = 0.f;
      #pragma unroll
      for (int wv = 0; wv < NWAVE; ++wv) {
        const float4 v = redc[wv][rl];
        S += v.x; S2 += v.y; SX += v.z;
      }
      S *= 0.5f; S2 *= 0.5f; SX *= 0.5f;   // ×2 lane duplication (n, n+8)
      const float spn  = sqrtf(S2);
      const float ispn = 1.f / (spn + 1e-8f);
      #pragma unroll
      for (int mt = 0; mt < 4; ++mt)
        #pragma unroll
        for (int q = 0; q < 4; ++q)
          fs[mt][q] *= ispn;
      smean_lane = S * ispn;

      if ((l & 15) < RB) {                 // publish f16 state for next B-frags
        #pragma unroll
        for (int mt = 0; mt < 4; ++mt) {
          const int i0 = wbase + mt * 16 + g * 4;
          uint2 pkv;
          pkv.x = pkh2(fs[mt][0], fs[mt][1]);
          pkv.y = pkh2(fs[mt][2], fs[mt][3]);
          *(uint2*)&srow[rl * SROW_ST + (i0 >> 1)] = pkv;
        }
      }

      if (last) {
        const float fnorm = spn * ispn;                 // ||fast||
        const float sdf   = SX * ispn;                  // slow·fast
        const float sn2   = 0.9025f * sl2_lane + 0.095f * sdf
                          + 0.0025f * fnorm * fnorm;
        const float sn    = sqrtf(fmaxf(sn2, 0.f));
        const float scale = (sn > 0.5f) ? 0.5f / (sn + 1e-12f) : 1.f;
        #pragma unroll
        for (int mt = 0; mt < 4; ++mt)
          #pragma unroll
          for (int q = 0; q < 4; ++q)
            sl[mt][q] = (0.95f * sl[mt][q] + 0.05f * fs[mt][q]) * scale;
        sl2_lane = sn2 * scale * scale;
        if (w == 0 && l < RB)
          carryl[l] = make_float4(S * ispn, fnorm, sl2_lane, 0.f);
        if ((l & 15) < RB) {
          #pragma unroll
          for (int mt = 0; mt < 4; ++mt) {
            const int i0 = wbase + mt * 16 + g * 4;
            *(float4*)&fastl[rl * F32_ST + i0] =
                make_float4(fs[mt][0], fs[mt][1], fs[mt][2], fs[mt][3]);
            if (t == TLEN - 1) {
              *(float4*)&comb_out[(size_t)(row0 + rl) * DDIM + i0] =
                  make_float4(fs[mt][0] + 0.3f * sl[mt][0],
                              fs[mt][1] + 0.3f * sl[mt][1],
                              fs[mt][2] + 0.3f * sl[mt][2],
                              fs[mt][3] + 0.3f * sl[mt][3]);
            }
          }
        }
      }
      __syncthreads();
    } // conv steps

    #pragma unroll
    for (int r = 0; r < RB; ++r) evc[r] = evn[r];
  } // tokens
}

// ---- readout GEMM: out[b][v] = Σ_d comb[b][d]·W[v][d] -----------------------
#define KC  32
#define LDT 132

__global__ __launch_bounds__(256) void logits_gemm(
    const float* __restrict__ comb,   // [256][512]
    const float* __restrict__ W,      // [32000][512]
    float*       __restrict__ out)    // [256][32000]
{
  __shared__ float wt[KC * LDT];
  __shared__ float ct[KC * LDT];

  const int tid = threadIdx.x;
  const int v0  = blockIdx.x * 128;
  const int b0  = blockIdx.y * 128;
  const int tb  = tid >> 4;
  const int tv  = tid & 15;

  float acc[8][8];
  #pragma unroll
  for (int a = 0; a < 8; ++a)
    #pragma unroll
    for (int b = 0; b < 8; ++b) acc[a][b] = 0.f;

  for (int kk = 0; kk < DDIM; kk += KC) {
    #pragma unroll
    for (int it = 0; it < 4; ++it) {
      const int l4  = tid + it * 256;
      const int row = l4 >> 3;
      const int k4  = (l4 & 7) << 2;
      const float4 gw = *(const float4*)&W[(size_t)(v0 + row) * DDIM + kk + k4];
      const float4 gc = *(const float4*)&comb[(size_t)(b0 + row) * DDIM + kk + k4];
      wt[(k4 + 0) * LDT + row] = gw.x;
      wt[(k4 + 1) * LDT + row] = gw.y;
      wt[(k4 + 2) * LDT + row] = gw.z;
      wt[(k4 + 3) * LDT + row] = gw.w;
      ct[(k4 + 0) * LDT + row] = gc.x;
      ct[(k4 + 1) * LDT + row] = gc.y;
      ct[(k4 + 2) * LDT + row] = gc.z;
      ct[(k4 + 3) * LDT + row] = gc.w;
    }
    __syncthreads();

    for (int kx = 0; kx < KC; ++kx) {
      const float4 c0 = *(const float4*)&ct[kx * LDT + tb * 8];
      const float4 c1 = *(const float4*)&ct[kx * LDT + tb * 8 + 4];
      const float4 w0 = *(const float4*)&wt[kx * LDT + tv * 8];
      const float4 w1 = *(const float4*)&wt[kx * LDT + tv * 8 + 4];
      const float cw[8] = {c0.x, c0.y, c0.z, c0.w, c1.x, c1.y, c1.z, c1.w};
      const float wv[8] = {w0.x, w0.y, w0.z, w0.w, w1.x, w1.y, w1.z, w1.w};
      #pragma unroll
      for (int ib = 0; ib < 8; ++ib)
        #pragma unroll
        for (int iv = 0; iv < 8; ++iv)
          acc[ib][iv] = fmaf(cw[ib], wv[iv], acc[ib][iv]);
    }
    __syncthreads();
  }

  #pragma unroll
  for (int ib = 0; ib < 8; ++ib) {
    const size_t base = (size_t)(b0 + tb * 8 + ib) * VDIM + v0 + tv * 8;
    *(float4*)&out[base]     = make_float4(acc[ib][0], acc[ib][1], acc[ib][2], acc[ib][3]);
    *(float4*)&out[base + 4] = make_float4(acc[ib][4], acc[ib][5], acc[ib][6], acc[ib][7]);
  }
}

extern "C" void kernel_launch(void* const* d_in, const int* in_sizes, int n_in,
                              void* d_out, int out_size, void* d_ws, size_t ws_size,
                              hipStream_t stream) {
  const int*   tokens    = (const int*)d_in[0];
  const float* embed     = (const float*)d_in[1];
  const float* readout_w = (const float*)d_in[2];
  const float* diffusion = (const float*)d_in[3];
  const float* gamma_p   = (const float*)d_in[4];
  const float* beta_p    = (const float*)d_in[5];

  float* comb = (float*)d_ws;                              // 512 KB
  uint4* Apk  = (uint4*)((char*)d_ws + 512 * 1024);        // 512 KB

  hipLaunchKernelGGL(pack_diffusion, dim3(128), dim3(256), 0, stream,
                     diffusion, Apk);
  hipLaunchKernelGGL(attractor_recurrence, dim3(NWG), dim3(512), 0, stream,
                     tokens, embed, Apk, gamma_p, beta_p, comb);
  hipLaunchKernelGGL(logits_gemm, dim3(VDIM / 128, 256 / 128), dim3(256), 0, stream,
                     comb, readout_w, (float*)d_out);
}